// Round 17
// baseline (669.945 us; speedup 1.0000x reference)
//
#include <hip/hip_runtime.h>

#define N_VEC 131072
#define DIM 256
#define KCODES 512
#define NUM_VQ 4

constexpr float BETA = 0.2f;
constexpr int BM = 64;
constexpr int NTHREADS = 512;          // 8 waves
constexpr int NBLOCKS = N_VEC / BM;    // 2048
constexpr float WMARGIN = 1.0f;        // 2x generous bound on |coarse - exact| score error
constexpr int MAXCAND = 24;

typedef short bf16x8 __attribute__((ext_vector_type(8)));
typedef float f32x4  __attribute__((ext_vector_type(4)));

__device__ __forceinline__ unsigned short f2bf(float x) {
    unsigned u = __builtin_bit_cast(unsigned, x);
    u += 0x7FFF + ((u >> 16) & 1);          // round-to-nearest-even
    return (unsigned short)(u >> 16);
}
__device__ __forceinline__ float bf2f(unsigned short h) {
    unsigned u = ((unsigned)h) << 16;
    return __builtin_bit_cast(float, u);
}
// order-preserving float<->uint for atomicMin (exact for all finite floats)
__device__ __forceinline__ unsigned enc_f(float f) {
    unsigned u = __builtin_bit_cast(unsigned, f);
    return (u & 0x80000000u) ? ~u : (u | 0x80000000u);
}
__device__ __forceinline__ float dec_f(unsigned e) {
    unsigned u = (e & 0x80000000u) ? (e ^ 0x80000000u) : ~e;
    return __builtin_bit_cast(float, u);
}

// ---------------- codebook norms (exact fp32) + hist zeroing ----------------
__global__ void norms_kernel(const float* __restrict__ cb, float* __restrict__ norms,
                             int* __restrict__ hist) {
    if (blockIdx.x < 8) hist[blockIdx.x * 256 + threadIdx.x] = 0;
    int row = blockIdx.x * 4 + (threadIdx.x >> 6);
    int lane = threadIdx.x & 63;
    const float* r = cb + (size_t)row * DIM;
    float4 v = *(const float4*)(r + lane * 4);
    float s = v.x * v.x + v.y * v.y + v.z * v.z + v.w * v.w;
    #pragma unroll
    for (int off = 32; off; off >>= 1) s += __shfl_down(s, off);
    if (lane == 0) norms[row] = s;
}

// ---------------- codebook -> fragment-granule bf16 HI image (1MB) ----------------
// B'[s][ks][ct][lane] : 16B granule = 8 bf16 of col = ct*16+(lane&15),
// k = ks*32 + (lane>>4)*8 .. +8
__global__ void bprep_kernel(const float* __restrict__ cb, char* __restrict__ bp) {
    int id = blockIdx.x * 256 + threadIdx.x;   // 65536 total
    int lane = id & 63;
    int ct   = (id >> 6) & 31;
    int ks   = (id >> 11) & 7;
    int s    = id >> 14;
    int col  = ct * 16 + (lane & 15);
    int kb   = ks * 32 + (lane >> 4) * 8;
    const float* src = cb + ((size_t)(s * KCODES + col)) * DIM + kb;
    float4 v0 = *(const float4*)src;
    float4 v1 = *(const float4*)(src + 4);
    float xs[8] = {v0.x, v0.y, v0.z, v0.w, v1.x, v1.y, v1.z, v1.w};
    bf16x8 o;
    #pragma unroll
    for (int i = 0; i < 8; ++i) o[i] = (short)f2bf(xs[i]);
    size_t off = (((size_t)(s * 8 + ks)) * 32 + ct) * 1024 + (size_t)lane * 16;
    *(bf16x8*)(bp + off) = o;
}

// ---------------- fused 4-stage residual VQ (coarse GEMM + exact rescore) ----------------
__global__ __launch_bounds__(NTHREADS, 4)
void vq_fused(const float* __restrict__ x,
              const char* __restrict__ bp,     // B' hi image (1MB)
              const float* __restrict__ cb,    // fp32 codebooks [4][512][256]
              const float* __restrict__ norms, // [4][512] exact
              float* __restrict__ out,         // q base, row stride 1024
              float* __restrict__ sq_partials, // [2048*8] one per wave
              int* __restrict__ hist,          // [4][512]
              const int* __restrict__ emap,
              float* __restrict__ logits)
{
    __shared__ __align__(16) char Ahi[32768];
    __shared__ __align__(16) char Alo[32768];
    __shared__ float ns[KCODES];
    __shared__ unsigned smin_u[BM];
    __shared__ int   cnt[BM];
    __shared__ int   cand[BM][MAXCAND];
    __shared__ int   sidx[BM];

    const int tid  = threadIdx.x;
    const int w    = tid >> 6;         // wave 0..7, owns cols [w*64, w*64+64)
    const int lane = tid & 63;
    const int l15  = lane & 15;
    const int h16  = lane >> 4;        // 0..3
    const long row0 = (long)blockIdx.x * BM;

    // ---- stage A once: 64x256 fp32 -> hi/lo bf16, XOR-swizzled ----
    #pragma unroll
    for (int e = 0; e < 4; ++e) {
        int ga = e * 512 + tid;        // 2048 granules
        int row = ga >> 5, k8 = ga & 31;
        const float* src = x + (row0 + row) * (long)DIM + k8 * 8;
        float4 v0 = *(const float4*)src;
        float4 v1 = *(const float4*)(src + 4);
        float xs[8] = {v0.x, v0.y, v0.z, v0.w, v1.x, v1.y, v1.z, v1.w};
        bf16x8 h, l;
        #pragma unroll
        for (int i = 0; i < 8; ++i) {
            unsigned short hb = f2bf(xs[i]);
            h[i] = (short)hb;
            l[i] = (short)f2bf(xs[i] - bf2f(hb));
        }
        int off = (row << 9) + ((k8 ^ (row & 7)) << 4);
        *(bf16x8*)(Ahi + off) = h;
        *(bf16x8*)(Alo + off) = l;
    }

    float lsq_acc = 0.f;

    #pragma unroll 1
    for (int s = 0; s < NUM_VQ; ++s) {
        ns[tid] = norms[s * KCODES + tid];
        if (tid < BM) { smin_u[tid] = 0xFFFFFFFFu; cnt[tid] = 0; }
        __syncthreads();   // A planes + ns + init ready

        // ---- coarse GEMM: 1 bf16 product (xhi . chi); no scheduling fences ----
        f32x4 acc[4][4];
        #pragma unroll
        for (int t = 0; t < 4; ++t)
            #pragma unroll
            for (int c = 0; c < 4; ++c)
                acc[t][c] = (f32x4){0.f, 0.f, 0.f, 0.f};

        const char* bw = bp + (size_t)s * 262144 + (size_t)(w * 4) * 1024 + (size_t)lane * 16;

        #pragma unroll
        for (int ks = 0; ks < 8; ++ks) {
            bf16x8 ah[4];
            #pragma unroll
            for (int t = 0; t < 4; ++t) {
                int row = t * 16 + l15;
                int k8  = ks * 4 + h16;
                int off = (row << 9) + ((k8 ^ (row & 7)) << 4);
                ah[t] = *(const bf16x8*)(Ahi + off);
            }
            #pragma unroll
            for (int c = 0; c < 4; ++c) {
                bf16x8 bh = *(const bf16x8*)(bw + (size_t)ks * 32768 + (size_t)c * 1024);
                #pragma unroll
                for (int t = 0; t < 4; ++t)
                    acc[t][c] = __builtin_amdgcn_mfma_f32_16x16x32_bf16(ah[t], bh, acc[t][c], 0, 0, 0);
            }
        }

        // ---- transform acc -> coarse scores in place (ns cached in regs) ----
        float nsc[4];
        #pragma unroll
        for (int c = 0; c < 4; ++c) nsc[c] = ns[w * 64 + c * 16 + l15];
        #pragma unroll
        for (int t = 0; t < 4; ++t)
            #pragma unroll
            for (int c = 0; c < 4; ++c)
                #pragma unroll
                for (int r = 0; r < 4; ++r)
                    acc[t][c][r] = nsc[c] - 2.0f * acc[t][c][r];

        // ---- per-row min via LDS atomicMin (order-preserving uint) ----
        #pragma unroll
        for (int t = 0; t < 4; ++t) {
            #pragma unroll
            for (int r = 0; r < 4; ++r) {
                float bv = fminf(fminf(acc[t][0][r], acc[t][1][r]),
                                 fminf(acc[t][2][r], acc[t][3][r]));
                #pragma unroll
                for (int m = 1; m < 16; m <<= 1)
                    bv = fminf(bv, __shfl_xor(bv, m));
                if (l15 == 0)
                    atomicMin(&smin_u[t * 16 + h16 * 4 + r], enc_f(bv));
            }
        }
        __syncthreads();

        // ---- candidate scan: coarse score <= min + W ----
        #pragma unroll
        for (int t = 0; t < 4; ++t) {
            #pragma unroll
            for (int r = 0; r < 4; ++r) {
                int row = t * 16 + h16 * 4 + r;
                float thr = dec_f(smin_u[row]) + WMARGIN;
                #pragma unroll
                for (int c = 0; c < 4; ++c) {
                    if (acc[t][c][r] <= thr) {
                        int pos = atomicAdd(&cnt[row], 1);
                        if (pos < MAXCAND) cand[row][pos] = w * 64 + c * 16 + l15;
                    }
                }
            }
        }
        __syncthreads();

        // ---- exact fp32 rescore (wave w owns rows w*8..w*8+7) ----
        const float* cbs_s = cb + (size_t)s * KCODES * DIM;
        #pragma unroll 1
        for (int i = 0; i < 8; ++i) {
            int row = w * 8 + i;
            int n = cnt[row]; if (n > MAXCAND) n = MAXCAND;
            if (n == 1) {
                if (lane == 0) sidx[row] = cand[row][0];
                continue;
            }
            float bs = 3.4e38f; int bcol = KCODES;
            int g  = lane >> 4;     // candidate slot within batch of 4
            int lg = lane & 15;     // 16 dim-groups within candidate
            for (int j0 = 0; j0 < n; j0 += 4) {
                int j = j0 + g;
                int col = cand[row][(j < n) ? j : 0];
                float part = 0.f;
                #pragma unroll
                for (int gg = 0; gg < 2; ++gg) {
                    int k8 = lg + 16 * gg;       // conflict-free LDS slots, contiguous cb
                    int off = (row << 9) + ((k8 ^ (row & 7)) << 4);
                    bf16x8 h = *(const bf16x8*)(Ahi + off);
                    bf16x8 l = *(const bf16x8*)(Alo + off);
                    const float* cp = cbs_s + (size_t)col * DIM + k8 * 8;
                    float4 c0 = *(const float4*)cp;
                    float4 c1 = *(const float4*)(cp + 4);
                    float cs[8] = {c0.x, c0.y, c0.z, c0.w, c1.x, c1.y, c1.z, c1.w};
                    #pragma unroll
                    for (int d = 0; d < 8; ++d) {
                        float xv = bf2f((unsigned short)h[d]) + bf2f((unsigned short)l[d]);
                        part += xv * cs[d];
                    }
                }
                #pragma unroll
                for (int m = 1; m < 16; m <<= 1) part += __shfl_xor(part, m);
                float sc = ns[col] - 2.0f * part;
                #pragma unroll
                for (int m = 16; m < 64; m <<= 1) {
                    float ov = __shfl_xor(sc, m);
                    int   ok = __shfl_xor(col, m);
                    if (ov < sc || (ov == sc && ok < col)) { sc = ov; col = ok; }
                }
                if (sc < bs || (sc == bs && col < bcol)) { bs = sc; bcol = col; }
            }
            if (lane == 0) sidx[row] = bcol;
        }
        __syncthreads();

        // ---- epilogue: gather fp32 code row (in-loop loads), q = code row,
        //      residual update in LDS, loss ----
        const int lrow = tid >> 3;          // 8 threads per row
        const int kidx = sidx[lrow];
        const long grow = row0 + lrow;
        const float* cbr = cb + ((size_t)s * KCODES + kidx) * DIM;
        float* qr = out + grow * 1024 + s * DIM;
        #pragma unroll
        for (int e = 0; e < 4; ++e) {
            int k8 = (tid & 7) + 8 * e;     // 4 granules per thread
            int off = (lrow << 9) + ((k8 ^ (lrow & 7)) << 4);
            float4 c0 = *(const float4*)(cbr + k8 * 8);
            float4 c1 = *(const float4*)(cbr + k8 * 8 + 4);
            bf16x8 h = *(const bf16x8*)(Ahi + off);
            bf16x8 l = *(const bf16x8*)(Alo + off);
            float cs[8] = {c0.x, c0.y, c0.z, c0.w, c1.x, c1.y, c1.z, c1.w};
            float rv[8];
            #pragma unroll
            for (int i = 0; i < 8; ++i) {
                float xv = bf2f((unsigned short)h[i]) + bf2f((unsigned short)l[i]);
                rv[i] = xv - cs[i];
                lsq_acc += rv[i] * rv[i];
            }
            *(float4*)(qr + k8 * 8)     = c0;
            *(float4*)(qr + k8 * 8 + 4) = c1;
            if (s < NUM_VQ - 1) {
                bf16x8 nh, nl;
                #pragma unroll
                for (int i = 0; i < 8; ++i) {
                    unsigned short hb = f2bf(rv[i]);
                    nh[i] = (short)hb;
                    nl[i] = (short)f2bf(rv[i] - bf2f(hb));
                }
                *(bf16x8*)(Ahi + off) = nh;
                *(bf16x8*)(Alo + off) = nl;
            }
        }

        if (tid < BM) atomicAdd(&hist[s * KCODES + sidx[tid]], 1);
        if (s == 0 && tid < BM) logits[row0 + tid] = (float)emap[sidx[tid]];
        // next stage's top barrier protects Ahi/Alo + ns + smin/cnt init
    }

    // wave-level loss partial (deterministic; one slot per wave)
    #pragma unroll
    for (int off = 32; off; off >>= 1) lsq_acc += __shfl_down(lsq_acc, off);
    if (lane == 0) sq_partials[blockIdx.x * 8 + w] = lsq_acc;
}

// ---------------- finalize: loss + perplexities ----------------
__global__ void finalize_kernel(const float* __restrict__ sq_partials,  // [16384]
                                const int* __restrict__ hist,
                                float* __restrict__ loss_out,
                                float* __restrict__ perp_out)
{
    __shared__ float sred[8];
    int tid = threadIdx.x;  // 512
    float s = 0.f;
    for (int i = tid; i < NBLOCKS * 8; i += 512) s += sq_partials[i];
    #pragma unroll
    for (int off = 32; off; off >>= 1) s += __shfl_down(s, off);
    if ((tid & 63) == 0) sred[tid >> 6] = s;
    __syncthreads();
    if (tid == 0) {
        float t = 0.f;
        for (int i = 0; i < 8; ++i) t += sred[i];
        *loss_out = (1.f + BETA) * t / ((float)N_VEC * (float)DIM);
    }
    for (int st = 0; st < NUM_VQ; ++st) {
        __syncthreads();
        float e = (float)hist[st * 512 + tid] * (1.f / (float)N_VEC);
        float term = e * logf(e + 1e-10f);
        #pragma unroll
        for (int off = 32; off; off >>= 1) term += __shfl_down(term, off);
        if ((tid & 63) == 0) sred[tid >> 6] = term;
        __syncthreads();
        if (tid == 0) {
            float t = 0.f;
            for (int i = 0; i < 8; ++i) t += sred[i];
            perp_out[st] = expf(-t);
        }
    }
}

extern "C" void kernel_launch(void* const* d_in, const int* in_sizes, int n_in,
                              void* d_out, int out_size, void* d_ws, size_t ws_size,
                              hipStream_t stream) {
    const float* x    = (const float*)d_in[0];
    const float* cbs  = (const float*)d_in[1];
    const int*   emap = (const int*)d_in[2];
    float* out = (float*)d_out;

    const size_t QSZ = (size_t)N_VEC * (NUM_VQ * DIM);
    float* loss_out = out + QSZ;
    float* logits   = out + QSZ + 1;
    float* perp     = out + QSZ + 1 + N_VEC;

    // ws: sq_partials[2048*8] f32 | hist[4*512] i32 | norms[2048] f32 | B' 1MB
    float* sq_partials = (float*)d_ws;
    int*   hist        = (int*)(sq_partials + NBLOCKS * 8);
    float* norms       = (float*)(hist + NUM_VQ * KCODES);
    char*  bprep       = (char*)(norms + NUM_VQ * KCODES);

    norms_kernel<<<NUM_VQ * KCODES / 4, 256, 0, stream>>>(cbs, norms, hist);
    bprep_kernel<<<256, 256, 0, stream>>>(cbs, bprep);

    vq_fused<<<NBLOCKS, NTHREADS, 0, stream>>>(
        x, bprep, cbs, norms, out, sq_partials, hist, emap, logits);

    finalize_kernel<<<1, 512, 0, stream>>>(sq_partials, hist, loss_out, perp);
}

// Round 18
// 483.710 us; speedup vs baseline: 1.3850x; 1.3850x over previous
//
#include <hip/hip_runtime.h>

#define N_VEC 131072
#define DIM 256
#define KCODES 512
#define NUM_VQ 4

constexpr float BETA = 0.2f;
constexpr int BM = 64;
constexpr int NTHREADS = 512;          // 8 waves
constexpr int NBLOCKS = N_VEC / BM;    // 2048
constexpr float WMARGIN = 1.0f;        // 2x generous bound on |coarse - exact| score error
constexpr int MAXCAND = 24;

typedef short bf16x8 __attribute__((ext_vector_type(8)));
typedef float f32x4  __attribute__((ext_vector_type(4)));

__device__ __forceinline__ unsigned short f2bf(float x) {
    unsigned u = __builtin_bit_cast(unsigned, x);
    u += 0x7FFF + ((u >> 16) & 1);          // round-to-nearest-even
    return (unsigned short)(u >> 16);
}
__device__ __forceinline__ float bf2f(unsigned short h) {
    unsigned u = ((unsigned)h) << 16;
    return __builtin_bit_cast(float, u);
}

// ---------------- codebook norms (exact fp32) + hist zeroing ----------------
__global__ void norms_kernel(const float* __restrict__ cb, float* __restrict__ norms,
                             int* __restrict__ hist) {
    if (blockIdx.x < 8) hist[blockIdx.x * 256 + threadIdx.x] = 0;
    int row = blockIdx.x * 4 + (threadIdx.x >> 6);
    int lane = threadIdx.x & 63;
    const float* r = cb + (size_t)row * DIM;
    float4 v = *(const float4*)(r + lane * 4);
    float s = v.x * v.x + v.y * v.y + v.z * v.z + v.w * v.w;
    #pragma unroll
    for (int off = 32; off; off >>= 1) s += __shfl_down(s, off);
    if (lane == 0) norms[row] = s;
}

// ---------------- codebook -> fragment-granule bf16 HI image (1MB) ----------------
// B'[s][ks][ct][lane] : 16B granule = 8 bf16 of col = ct*16+(lane&15),
// k = ks*32 + (lane>>4)*8 .. +8
__global__ void bprep_kernel(const float* __restrict__ cb, char* __restrict__ bp) {
    int id = blockIdx.x * 256 + threadIdx.x;   // 65536 total
    int lane = id & 63;
    int ct   = (id >> 6) & 31;
    int ks   = (id >> 11) & 7;
    int s    = id >> 14;
    int col  = ct * 16 + (lane & 15);
    int kb   = ks * 32 + (lane >> 4) * 8;
    const float* src = cb + ((size_t)(s * KCODES + col)) * DIM + kb;
    float4 v0 = *(const float4*)src;
    float4 v1 = *(const float4*)(src + 4);
    float xs[8] = {v0.x, v0.y, v0.z, v0.w, v1.x, v1.y, v1.z, v1.w};
    bf16x8 o;
    #pragma unroll
    for (int i = 0; i < 8; ++i) o[i] = (short)f2bf(xs[i]);
    size_t off = (((size_t)(s * 8 + ks)) * 32 + ct) * 1024 + (size_t)lane * 16;
    *(bf16x8*)(bp + off) = o;
}

// ---------------- fused 4-stage residual VQ (coarse GEMM + exact rescore) ----------------
__global__ __launch_bounds__(NTHREADS, 4)
void vq_fused(const float* __restrict__ x,
              const char* __restrict__ bp,     // B' hi image (1MB)
              const float* __restrict__ cb,    // fp32 codebooks [4][512][256]
              const float* __restrict__ norms, // [4][512] exact
              float* __restrict__ out,         // q base, row stride 1024
              float* __restrict__ sq_partials, // [2048*8] one per wave
              int* __restrict__ hist,          // [4][512]
              const int* __restrict__ emap,
              float* __restrict__ logits)
{
    __shared__ __align__(16) char Ahi[32768];
    __shared__ __align__(16) char Alo[32768];
    __shared__ float ns[KCODES];
    __shared__ float wmin[8][BM];
    __shared__ float smin[BM];
    __shared__ int   cnt[BM];
    __shared__ int   cand[BM][MAXCAND];
    __shared__ int   sidx[BM];

    const int tid  = threadIdx.x;
    const int w    = tid >> 6;         // wave 0..7, owns cols [w*64, w*64+64)
    const int lane = tid & 63;
    const int l15  = lane & 15;
    const int h16  = lane >> 4;        // 0..3
    const long row0 = (long)blockIdx.x * BM;

    // ---- stage A once: 64x256 fp32 -> hi/lo bf16, XOR-swizzled ----
    #pragma unroll
    for (int e = 0; e < 4; ++e) {
        int ga = e * 512 + tid;        // 2048 granules
        int row = ga >> 5, k8 = ga & 31;
        const float* src = x + (row0 + row) * (long)DIM + k8 * 8;
        float4 v0 = *(const float4*)src;
        float4 v1 = *(const float4*)(src + 4);
        float xs[8] = {v0.x, v0.y, v0.z, v0.w, v1.x, v1.y, v1.z, v1.w};
        bf16x8 h, l;
        #pragma unroll
        for (int i = 0; i < 8; ++i) {
            unsigned short hb = f2bf(xs[i]);
            h[i] = (short)hb;
            l[i] = (short)f2bf(xs[i] - bf2f(hb));
        }
        int off = (row << 9) + ((k8 ^ (row & 7)) << 4);
        *(bf16x8*)(Ahi + off) = h;
        *(bf16x8*)(Alo + off) = l;
    }

    float lsq_acc = 0.f;

    #pragma unroll 1
    for (int s = 0; s < NUM_VQ; ++s) {
        ns[tid] = norms[s * KCODES + tid];
        __syncthreads();   // A planes + ns ready

        // ---- coarse GEMM: 1 bf16 product (xhi . chi); no scheduling fences ----
        f32x4 acc[4][4];
        #pragma unroll
        for (int t = 0; t < 4; ++t)
            #pragma unroll
            for (int c = 0; c < 4; ++c)
                acc[t][c] = (f32x4){0.f, 0.f, 0.f, 0.f};

        const char* bw = bp + (size_t)s * 262144 + (size_t)(w * 4) * 1024 + (size_t)lane * 16;

        #pragma unroll
        for (int ks = 0; ks < 8; ++ks) {
            bf16x8 ah[4];
            #pragma unroll
            for (int t = 0; t < 4; ++t) {
                int row = t * 16 + l15;
                int k8  = ks * 4 + h16;
                int off = (row << 9) + ((k8 ^ (row & 7)) << 4);
                ah[t] = *(const bf16x8*)(Ahi + off);
            }
            #pragma unroll
            for (int c = 0; c < 4; ++c) {
                bf16x8 bh = *(const bf16x8*)(bw + (size_t)ks * 32768 + (size_t)c * 1024);
                #pragma unroll
                for (int t = 0; t < 4; ++t)
                    acc[t][c] = __builtin_amdgcn_mfma_f32_16x16x32_bf16(ah[t], bh, acc[t][c], 0, 0, 0);
            }
        }

        // ---- transform acc -> coarse scores in place (ns cached in regs) ----
        float nsc[4];
        #pragma unroll
        for (int c = 0; c < 4; ++c) nsc[c] = ns[w * 64 + c * 16 + l15];
        #pragma unroll
        for (int t = 0; t < 4; ++t)
            #pragma unroll
            for (int c = 0; c < 4; ++c)
                #pragma unroll
                for (int r = 0; r < 4; ++r)
                    acc[t][c][r] = nsc[c] - 2.0f * acc[t][c][r];

        // ---- coarse per-row min (value only) ----
        #pragma unroll
        for (int t = 0; t < 4; ++t) {
            #pragma unroll
            for (int r = 0; r < 4; ++r) {
                float bv = fminf(fminf(acc[t][0][r], acc[t][1][r]),
                                 fminf(acc[t][2][r], acc[t][3][r]));
                #pragma unroll
                for (int m = 1; m < 16; m <<= 1)
                    bv = fminf(bv, __shfl_xor(bv, m));
                if (l15 == 0) wmin[w][t * 16 + h16 * 4 + r] = bv;
            }
        }
        __syncthreads();
        if (tid < BM) {
            float bv = wmin[0][tid];
            #pragma unroll
            for (int q2 = 1; q2 < 8; ++q2) bv = fminf(bv, wmin[q2][tid]);
            smin[tid] = bv;
            cnt[tid] = 0;
        }
        __syncthreads();

        // ---- candidate scan: coarse score <= min + W ----
        #pragma unroll
        for (int t = 0; t < 4; ++t) {
            #pragma unroll
            for (int r = 0; r < 4; ++r) {
                int row = t * 16 + h16 * 4 + r;
                float thr = smin[row] + WMARGIN;
                #pragma unroll
                for (int c = 0; c < 4; ++c) {
                    if (acc[t][c][r] <= thr) {
                        int pos = atomicAdd(&cnt[row], 1);
                        if (pos < MAXCAND) cand[row][pos] = w * 64 + c * 16 + l15;
                    }
                }
            }
        }
        __syncthreads();

        // ---- exact fp32 rescore (wave w owns rows w*8..w*8+7) ----
        const float* cbs_s = cb + (size_t)s * KCODES * DIM;
        #pragma unroll 1
        for (int i = 0; i < 8; ++i) {
            int row = w * 8 + i;
            int n = cnt[row]; if (n > MAXCAND) n = MAXCAND;
            if (n == 1) {
                if (lane == 0) sidx[row] = cand[row][0];
                continue;
            }
            float bs = 3.4e38f; int bcol = KCODES;
            int g  = lane >> 4;     // candidate slot within batch of 4
            int lg = lane & 15;     // 16 dim-groups within candidate
            for (int j0 = 0; j0 < n; j0 += 4) {
                int j = j0 + g;
                int col = cand[row][(j < n) ? j : 0];
                float part = 0.f;
                #pragma unroll
                for (int gg = 0; gg < 2; ++gg) {
                    int k8 = lg + 16 * gg;       // conflict-free LDS slots, contiguous cb
                    int off = (row << 9) + ((k8 ^ (row & 7)) << 4);
                    bf16x8 h = *(const bf16x8*)(Ahi + off);
                    bf16x8 l = *(const bf16x8*)(Alo + off);
                    const float* cp = cbs_s + (size_t)col * DIM + k8 * 8;
                    float4 c0 = *(const float4*)cp;
                    float4 c1 = *(const float4*)(cp + 4);
                    float cs[8] = {c0.x, c0.y, c0.z, c0.w, c1.x, c1.y, c1.z, c1.w};
                    #pragma unroll
                    for (int d = 0; d < 8; ++d) {
                        float xv = bf2f((unsigned short)h[d]) + bf2f((unsigned short)l[d]);
                        part += xv * cs[d];
                    }
                }
                #pragma unroll
                for (int m = 1; m < 16; m <<= 1) part += __shfl_xor(part, m);
                float sc = ns[col] - 2.0f * part;
                #pragma unroll
                for (int m = 16; m < 64; m <<= 1) {
                    float ov = __shfl_xor(sc, m);
                    int   ok = __shfl_xor(col, m);
                    if (ov < sc || (ov == sc && ok < col)) { sc = ov; col = ok; }
                }
                if (sc < bs || (sc == bs && col < bcol)) { bs = sc; bcol = col; }
            }
            if (lane == 0) sidx[row] = bcol;
        }
        __syncthreads();

        // ---- epilogue: gather fp32 code row (in-loop loads), q = code row,
        //      residual update in LDS, loss ----
        const int lrow = tid >> 3;          // 8 threads per row
        const int kidx = sidx[lrow];
        const long grow = row0 + lrow;
        const float* cbr = cb + ((size_t)s * KCODES + kidx) * DIM;
        float* qr = out + grow * 1024 + s * DIM;
        #pragma unroll
        for (int e = 0; e < 4; ++e) {
            int k8 = (tid & 7) + 8 * e;     // 4 granules per thread
            int off = (lrow << 9) + ((k8 ^ (lrow & 7)) << 4);
            float4 c0 = *(const float4*)(cbr + k8 * 8);
            float4 c1 = *(const float4*)(cbr + k8 * 8 + 4);
            bf16x8 h = *(const bf16x8*)(Ahi + off);
            bf16x8 l = *(const bf16x8*)(Alo + off);
            float cs[8] = {c0.x, c0.y, c0.z, c0.w, c1.x, c1.y, c1.z, c1.w};
            float rv[8];
            #pragma unroll
            for (int i = 0; i < 8; ++i) {
                float xv = bf2f((unsigned short)h[i]) + bf2f((unsigned short)l[i]);
                rv[i] = xv - cs[i];
                lsq_acc += rv[i] * rv[i];
            }
            *(float4*)(qr + k8 * 8)     = c0;
            *(float4*)(qr + k8 * 8 + 4) = c1;
            if (s < NUM_VQ - 1) {
                bf16x8 nh, nl;
                #pragma unroll
                for (int i = 0; i < 8; ++i) {
                    unsigned short hb = f2bf(rv[i]);
                    nh[i] = (short)hb;
                    nl[i] = (short)f2bf(rv[i] - bf2f(hb));
                }
                *(bf16x8*)(Ahi + off) = nh;
                *(bf16x8*)(Alo + off) = nl;
            }
        }

        if (tid < BM) atomicAdd(&hist[s * KCODES + sidx[tid]], 1);
        if (s == 0 && tid < BM) logits[row0 + tid] = (float)emap[sidx[tid]];
        // next stage's top barrier protects Ahi/Alo + ns
    }

    // wave-level loss partial (deterministic; one slot per wave)
    #pragma unroll
    for (int off = 32; off; off >>= 1) lsq_acc += __shfl_down(lsq_acc, off);
    if (lane == 0) sq_partials[blockIdx.x * 8 + w] = lsq_acc;
}

// ---------------- finalize: loss + perplexities ----------------
__global__ void finalize_kernel(const float* __restrict__ sq_partials,  // [16384]
                                const int* __restrict__ hist,
                                float* __restrict__ loss_out,
                                float* __restrict__ perp_out)
{
    __shared__ float sred[8];
    int tid = threadIdx.x;  // 512
    float s = 0.f;
    for (int i = tid; i < NBLOCKS * 8; i += 512) s += sq_partials[i];
    #pragma unroll
    for (int off = 32; off; off >>= 1) s += __shfl_down(s, off);
    if ((tid & 63) == 0) sred[tid >> 6] = s;
    __syncthreads();
    if (tid == 0) {
        float t = 0.f;
        for (int i = 0; i < 8; ++i) t += sred[i];
        *loss_out = (1.f + BETA) * t / ((float)N_VEC * (float)DIM);
    }
    for (int st = 0; st < NUM_VQ; ++st) {
        __syncthreads();
        float e = (float)hist[st * 512 + tid] * (1.f / (float)N_VEC);
        float term = e * logf(e + 1e-10f);
        #pragma unroll
        for (int off = 32; off; off >>= 1) term += __shfl_down(term, off);
        if ((tid & 63) == 0) sred[tid >> 6] = term;
        __syncthreads();
        if (tid == 0) {
            float t = 0.f;
            for (int i = 0; i < 8; ++i) t += sred[i];
            perp_out[st] = expf(-t);
        }
    }
}

extern "C" void kernel_launch(void* const* d_in, const int* in_sizes, int n_in,
                              void* d_out, int out_size, void* d_ws, size_t ws_size,
                              hipStream_t stream) {
    const float* x    = (const float*)d_in[0];
    const float* cbs  = (const float*)d_in[1];
    const int*   emap = (const int*)d_in[2];
    float* out = (float*)d_out;

    const size_t QSZ = (size_t)N_VEC * (NUM_VQ * DIM);
    float* loss_out = out + QSZ;
    float* logits   = out + QSZ + 1;
    float* perp     = out + QSZ + 1 + N_VEC;

    // ws: sq_partials[2048*8] f32 | hist[4*512] i32 | norms[2048] f32 | B' 1MB
    float* sq_partials = (float*)d_ws;
    int*   hist        = (int*)(sq_partials + NBLOCKS * 8);
    float* norms       = (float*)(hist + NUM_VQ * KCODES);
    char*  bprep       = (char*)(norms + NUM_VQ * KCODES);

    norms_kernel<<<NUM_VQ * KCODES / 4, 256, 0, stream>>>(cbs, norms, hist);
    bprep_kernel<<<256, 256, 0, stream>>>(cbs, bprep);

    vq_fused<<<NBLOCKS, NTHREADS, 0, stream>>>(
        x, bprep, cbs, norms, out, sq_partials, hist, emap, logits);

    finalize_kernel<<<1, 512, 0, stream>>>(sq_partials, hist, loss_out, perp);
}